// Round 5
// baseline (3765.204 us; speedup 1.0000x reference)
//
#include <hip/hip_runtime.h>
#include <hip/hip_bf16.h>
#include <stdint.h>

// ---------------- problem constants ----------------
#define TT 512
#define BB 256
#define HH 256
#define II 128
#define OUTD 128
#define EPSV 1e-5f

// ---------------- pipeline geometry ----------------
// 16 clusters x 16 batch rows; per cluster 4 stage-WGs of 512 threads:
//   M1: gi1 = x@Wih1^T (+all r/z biases)          [free-running producer]
//   A : gh1 recurrence, h1 state in own LDS       [serial chain 1]
//   M2: gi2 = h1@Wih2^T (+biases)                 [forward stage]
//   B : gh2 recurrence + h2seq + BN partials      [serial chain 2]
// Links: gi1(M1->A), h1(A->M2), gi2(M2->B) through 8-deep coherence-point rings.
// Protocol: cached counters + register-relay prefetch + raw barriers (no vmcnt
// drain at barriers!) + vmcnt(K)-certified delayed posts.
#define NCL 16
#define RPC 16
#define RD  8
#define HPAD 264

#define ST_M1 0
#define ST_A  1
#define ST_M2 2
#define ST_B  3

typedef short bf16x8 __attribute__((ext_vector_type(8)));
typedef short s16x4  __attribute__((ext_vector_type(4)));
typedef float f32x4  __attribute__((ext_vector_type(4)));
typedef unsigned long long u64;

// raw barrier: order LDS, sync waves, do NOT drain vmcnt (unlike __syncthreads)
#define BARRIER() asm volatile("s_waitcnt lgkmcnt(0)\n\ts_barrier" ::: "memory")
#define WAITV(N)  asm volatile("s_waitcnt vmcnt(" #N ")" ::: "memory")

// ---------------- workspace layout (bytes) ----------------
#define OFF_PROG     0u                          // 16 cl x 4 x u32 (padded)
#define OFF_BNSUM    1024u
#define OFF_BNSQ     2048u
#define OFF_ZERO_END 3072u
#define OFF_GI1      65536u
#define GI_SLOT      32768u                      // rz bf16 16KB + n fp32 16KB
#define GI_BYTES     (NCL*RD*GI_SLOT)            // 4 MB
#define OFF_GI2      (OFF_GI1 + GI_BYTES)
#define OFF_H1R      (OFF_GI2 + GI_BYTES)
#define H1_BYTES     (NCL*RD*8192u)              // 1 MB
#define OFF_H2P      (OFF_H1R + H1_BYTES)        // packed h2: 64 MB
#define OFF_XBF      (OFF_H2P + (unsigned)NCL*TT*8192u)
// + 32 MB xbf  => ~105.5 MB total

__device__ __forceinline__ short f2bf(float v) {
    unsigned u = __float_as_uint(v);
    u += 0x7fffu + ((u >> 16) & 1u);
    return (short)(u >> 16);
}
__device__ __forceinline__ float bf2f(short s) {
    return __uint_as_float(((unsigned)(unsigned short)s) << 16);
}
__device__ __forceinline__ bf16x8 ldfrag_f32(const float* __restrict__ p) {
    const float4* q = (const float4*)p;
    float4 a = q[0], b = q[1];
    bf16x8 f;
    f[0]=f2bf(a.x); f[1]=f2bf(a.y); f[2]=f2bf(a.z); f[3]=f2bf(a.w);
    f[4]=f2bf(b.x); f[5]=f2bf(b.y); f[6]=f2bf(b.z); f[7]=f2bf(b.w);
    return f;
}
__device__ __forceinline__ float clamp30(float x){ return fminf(fmaxf(x, -30.f), 30.f); }
__device__ __forceinline__ float sigm(float x){ x = clamp30(x); return 1.f/(1.f + __expf(-x)); }
__device__ __forceinline__ float tanh_f(float x){
    x = clamp30(x);
    float e = __expf(-2.f * x);
    return (1.f - e) / (1.f + e);
}
__device__ __forceinline__ u64 pack4bf(float a, float b, float c, float d) {
    u64 r = (u64)(unsigned short)f2bf(a);
    r |= (u64)(unsigned short)f2bf(b) << 16;
    r |= (u64)(unsigned short)f2bf(c) << 32;
    r |= (u64)(unsigned short)f2bf(d) << 48;
    return r;
}
__device__ __forceinline__ u64 ld_u64_coh(const u64* p) {
    return __hip_atomic_load((u64*)p, __ATOMIC_RELAXED, __HIP_MEMORY_SCOPE_SYSTEM);
}
__device__ __forceinline__ void st_u64_coh(u64* p, u64 v) {
    __hip_atomic_store(p, v, __ATOMIC_RELAXED, __HIP_MEMORY_SCOPE_SYSTEM);
}
__device__ __forceinline__ void post(unsigned* p, int v) {
    __hip_atomic_store(p, (unsigned)v, __ATOMIC_RELAXED, __HIP_MEMORY_SCOPE_SYSTEM);
}
// cached poll: only touches memory when the cached counter is insufficient
__device__ __forceinline__ void ensure(const unsigned* p, int tgt, int& cache) {
    if (cache >= tgt) return;
    for (;;) {
        int v = (int)__hip_atomic_load((unsigned*)p, __ATOMIC_RELAXED, __HIP_MEMORY_SCOPE_SYSTEM);
        if (v >= tgt) { cache = v; break; }
        __builtin_amdgcn_s_sleep(8);
    }
}

// relay payload: per block b2: rz = {r-packed bf16x4, z-packed bf16x4}, nn = fp32x4
struct RelA { u64 rz[2][2]; u64 nn[2][2]; };
__device__ __forceinline__ void ld_relay(RelA& R, const char* gi, int cl, int slot, int tid) {
    const u64* gb = (const u64*)(gi + ((size_t)cl*RD + slot)*GI_SLOT);
    #pragma unroll
    for (int b2 = 0; b2 < 2; ++b2) {
        R.rz[b2][0] = ld_u64_coh(gb + tid*4 + b2*2);
        R.rz[b2][1] = ld_u64_coh(gb + tid*4 + b2*2 + 1);
        R.nn[b2][0] = ld_u64_coh(gb + 2048 + tid*4 + b2*2);
        R.nn[b2][1] = ld_u64_coh(gb + 2048 + tid*4 + b2*2 + 1);
    }
}

// ---------------- x fp32 -> bf16 prepack ----------------
__global__ void cvt_x(const float* __restrict__ x, short* __restrict__ xbf, int n) {
    int i = (blockIdx.x * blockDim.x + threadIdx.x) * 4;
    if (i < n) {
        float4 v = *(const float4*)(x + i);
        s16x4 o; o[0]=f2bf(v.x); o[1]=f2bf(v.y); o[2]=f2bf(v.z); o[3]=f2bf(v.w);
        *(s16x4*)(xbf + i) = o;
    }
}

#define MFMA16(a,b,c) __builtin_amdgcn_mfma_f32_16x16x32_bf16(a,b,c,0,0,0)

// ---------------- persistent 4-stage pipeline ----------------
__global__ void __launch_bounds__(512, 2)
gru_pipe(const short* __restrict__ xbf,
         const float* __restrict__ wih1, const float* __restrict__ whh1,
         const float* __restrict__ bih1, const float* __restrict__ bhh1,
         const float* __restrict__ wih2, const float* __restrict__ whh2,
         const float* __restrict__ bih2, const float* __restrict__ bhh2,
         char* __restrict__ ws)
{
    const int tid  = threadIdx.x;
    const int wave = tid >> 6;
    const int lane = tid & 63;
    const int qd   = lane >> 4;
    const int ln   = lane & 15;

    const int bi    = blockIdx.x;
    const int clo   = bi & 7;
    const int jj    = bi >> 3;
    const int stage = jj & 3;
    const int chi   = jj >> 2;
    const int cl    = chi * 8 + clo;
    const int row0  = cl * RPC;

    unsigned* prog = (unsigned*)(ws + OFF_PROG) + cl * 4;
    unsigned* pM1 = &prog[ST_M1];
    unsigned* pA  = &prog[ST_A];
    unsigned* pM2 = &prog[ST_M2];
    unsigned* pB  = &prog[ST_B];

    __shared__ __align__(16) short hb[2][16][HPAD];

    if (stage == ST_M1) {
        // ============ M1: gi1 producer ============
        bf16x8 WR[2][4], WZ[2][4], WN[2][4];
        float bR[2], bZ[2], bN[2];
        #pragma unroll
        for (int b2 = 0; b2 < 2; ++b2) {
            const int cb = (2*wave + b2)*16 + ln;
            #pragma unroll
            for (int kc = 0; kc < 4; ++kc) {
                WR[b2][kc] = ldfrag_f32(wih1 + (0*256+cb)*II + kc*32 + qd*8);
                WZ[b2][kc] = ldfrag_f32(wih1 + (1*256+cb)*II + kc*32 + qd*8);
                WN[b2][kc] = ldfrag_f32(wih1 + (2*256+cb)*II + kc*32 + qd*8);
            }
            bR[b2] = bih1[cb]       + bhh1[cb];
            bZ[b2] = bih1[256 + cb] + bhh1[256 + cb];
            bN[b2] = bih1[512 + cb];
        }
        const short* xr = xbf + (row0 + ln) * (TT*II);
        char* gi1 = ws + OFF_GI1;
        int cA = 0;
        bf16x8 X0[4], X1[4];
        #pragma unroll
        for (int kc = 0; kc < 4; ++kc) X0[kc] = *(const bf16x8*)(xr + kc*32 + qd*8);
        __syncthreads();

        auto stepM1 = [&](int s, bf16x8 (&xc)[4], bf16x8 (&xn)[4]) {
            WAITV(11); BARRIER();
            if (tid == 0 && s >= 1) post(pM1, s - 1);
            if (s + 1 < TT) {
                #pragma unroll
                for (int kc = 0; kc < 4; ++kc)
                    xn[kc] = *(const bf16x8*)(xr + (s+1)*II + kc*32 + qd*8);
            }
            if ((s & 3) == 0) ensure(pA, s - 5, cA);
            f32x4 aR[2], aZ[2], aN[2];
            #pragma unroll
            for (int b2 = 0; b2 < 2; ++b2) {
                aR[b2] = f32x4{bR[b2],bR[b2],bR[b2],bR[b2]};
                aZ[b2] = f32x4{bZ[b2],bZ[b2],bZ[b2],bZ[b2]};
                aN[b2] = f32x4{bN[b2],bN[b2],bN[b2],bN[b2]};
            }
            #pragma unroll
            for (int kc = 0; kc < 4; ++kc) {
                aR[0] = MFMA16(xc[kc], WR[0][kc], aR[0]);
                aR[1] = MFMA16(xc[kc], WR[1][kc], aR[1]);
                aZ[0] = MFMA16(xc[kc], WZ[0][kc], aZ[0]);
                aZ[1] = MFMA16(xc[kc], WZ[1][kc], aZ[1]);
                aN[0] = MFMA16(xc[kc], WN[0][kc], aN[0]);
                aN[1] = MFMA16(xc[kc], WN[1][kc], aN[1]);
            }
            u64* gb = (u64*)(gi1 + ((size_t)cl*RD + (s & 7))*GI_SLOT);
            #pragma unroll
            for (int b2 = 0; b2 < 2; ++b2) {
                st_u64_coh(gb + tid*4 + b2*2,     pack4bf(aR[b2][0],aR[b2][1],aR[b2][2],aR[b2][3]));
                st_u64_coh(gb + tid*4 + b2*2 + 1, pack4bf(aZ[b2][0],aZ[b2][1],aZ[b2][2],aZ[b2][3]));
                union { f32x4 v; u64 u[2]; } nn; nn.v = aN[b2];
                st_u64_coh(gb + 2048 + tid*4 + b2*2,     nn.u[0]);
                st_u64_coh(gb + 2048 + tid*4 + b2*2 + 1, nn.u[1]);
            }
        };
        for (int s = 0; s < TT; s += 2) { stepM1(s, X0, X1); stepM1(s+1, X1, X0); }
        asm volatile("s_waitcnt vmcnt(0)" ::: "memory");
        __syncthreads();
        if (tid == 0) post(pM1, TT + 64);

    } else if (stage == ST_A || stage == ST_B) {
        // ============ A / B: recurrence stages ============
        const bool isA = (stage == ST_A);
        const float* Wh  = isA ? whh1 : whh2;
        const float* bhh = isA ? bhh1 : bhh2;
        const char*  gi  = ws + (isA ? OFF_GI1 : OFF_GI2);
        unsigned* availP = isA ? pM1 : pM2;     // upstream producer
        unsigned* myP    = isA ? pA  : pB;
        unsigned* bpP    = isA ? pM2 : (unsigned*)nullptr;  // A backpressured by M2
        u64* h1r  = (u64*)(ws + OFF_H1R);
        u64* h2p  = (u64*)(ws + OFF_H2P);
        float* bnsum = (float*)(ws + OFF_BNSUM);
        float* bnsq  = (float*)(ws + OFF_BNSQ);

        bf16x8 WR[2][8], WZ[2][8], WN[2][8];
        float bnn[2];
        #pragma unroll
        for (int b2 = 0; b2 < 2; ++b2) {
            const int cb = (2*wave + b2)*16 + ln;
            #pragma unroll
            for (int kc = 0; kc < 8; ++kc) {
                WR[b2][kc] = ldfrag_f32(Wh + (0*256+cb)*HH + kc*32 + qd*8);
                WZ[b2][kc] = ldfrag_f32(Wh + (1*256+cb)*HH + kc*32 + qd*8);
                WN[b2][kc] = ldfrag_f32(Wh + (2*256+cb)*HH + kc*32 + qd*8);
            }
            bnn[b2] = bhh[2*256 + cb];
        }
        float hold[2][4] = {{0,0,0,0},{0,0,0,0}};
        float bs[2] = {0,0}, bq[2] = {0,0};
        int cUp = 0, cBp = 0;
        { // zero h(-1) in hb[0]
            u64* z = (u64*)&hb[0][0][0];
            for (int i = tid; i < 16*HPAD/4; i += 512) z[i] = 0ull;
        }
        RelA R0, R1;
        ensure(availP, 1, cUp);
        ld_relay(R0, gi, cl, 0, tid);
        __syncthreads();

        auto stepR = [&](int t, RelA& cur, RelA& nxt) {
            if (isA) { WAITV(7); } else { WAITV(6); }
            BARRIER();
            if (tid == 0 && t >= 1) post(myP, t - 1);
            if (t + 1 < TT) { ensure(availP, t + 2, cUp); ld_relay(nxt, gi, cl, (t+1)&7, tid); }
            if (isA && (t & 3) == 0) ensure(bpP, t - 5, cBp);
            const int buf = t & 1;
            // phase 1: R,Z matmuls
            f32x4 aR[2] = {f32x4{0,0,0,0}, f32x4{0,0,0,0}};
            f32x4 aZ[2] = {f32x4{0,0,0,0}, f32x4{0,0,0,0}};
            #pragma unroll
            for (int kc = 0; kc < 8; ++kc) {
                bf16x8 f = *(const bf16x8*)&hb[buf][ln][kc*32 + qd*8];
                aR[0] = MFMA16(f, WR[0][kc], aR[0]);
                aR[1] = MFMA16(f, WR[1][kc], aR[1]);
                aZ[0] = MFMA16(f, WZ[0][kc], aZ[0]);
                aZ[1] = MFMA16(f, WZ[1][kc], aZ[1]);
            }
            f32x4 rg[2], zg[2];
            #pragma unroll
            for (int b2 = 0; b2 < 2; ++b2)
                #pragma unroll
                for (int j = 0; j < 4; ++j) {
                    rg[b2][j] = sigm(bf2f((short)(cur.rz[b2][0] >> (16*j))) + aR[b2][j]);
                    zg[b2][j] = sigm(bf2f((short)(cur.rz[b2][1] >> (16*j))) + aZ[b2][j]);
                }
            // phase 2: N matmul
            f32x4 aN[2];
            aN[0] = f32x4{bnn[0],bnn[0],bnn[0],bnn[0]};
            aN[1] = f32x4{bnn[1],bnn[1],bnn[1],bnn[1]};
            #pragma unroll
            for (int kc = 0; kc < 8; ++kc) {
                bf16x8 f = *(const bf16x8*)&hb[buf][ln][kc*32 + qd*8];
                aN[0] = MFMA16(f, WN[0][kc], aN[0]);
                aN[1] = MFMA16(f, WN[1][kc], aN[1]);
            }
            // combine + distribute
            #pragma unroll
            for (int b2 = 0; b2 < 2; ++b2) {
                const int colg = (2*wave + b2)*16 + ln;
                union { u64 u[2]; f32x4 v; } nn;
                nn.u[0] = cur.nn[b2][0]; nn.u[1] = cur.nn[b2][1];
                u64 pk = 0;
                #pragma unroll
                for (int r = 0; r < 4; ++r) {
                    float ng = tanh_f(nn.v[r] + rg[b2][r] * aN[b2][r]);
                    float h  = (1.f - zg[b2][r]) * ng + zg[b2][r] * hold[b2][r];
                    hold[b2][r] = h;
                    short hs = f2bf(h);
                    hb[1 - buf][qd*4 + r][colg] = hs;
                    pk |= (u64)(unsigned short)hs << (16*r);
                    if (!isA) { bs[b2] += h; bq[b2] += h*h; }
                }
                if (isA) {
                    st_u64_coh(h1r + ((size_t)cl*RD + (t & 7))*1024 + colg*4 + qd, pk);
                } else {
                    __builtin_nontemporal_store(pk, h2p + ((size_t)cl*TT + t)*1024 + colg*4 + qd);
                }
            }
        };
        for (int t = 0; t < TT; t += 2) { stepR(t, R0, R1); stepR(t+1, R1, R0); }
        if (!isA) {
            #pragma unroll
            for (int b2 = 0; b2 < 2; ++b2) {
                const int colg = (2*wave + b2)*16 + ln;
                atomicAdd(&bnsum[colg], bs[b2]);
                atomicAdd(&bnsq[colg],  bq[b2]);
            }
        }
        asm volatile("s_waitcnt vmcnt(0)" ::: "memory");
        __syncthreads();
        if (tid == 0) post(myP, TT + 64);

    } else {
        // ============ M2: gi2 = h1 @ Wih2^T ============
        bf16x8 WR[2][8], WZ[2][8], WN[2][8];
        float bR[2], bZ[2], bN[2];
        #pragma unroll
        for (int b2 = 0; b2 < 2; ++b2) {
            const int cb = (2*wave + b2)*16 + ln;
            #pragma unroll
            for (int kc = 0; kc < 8; ++kc) {
                WR[b2][kc] = ldfrag_f32(wih2 + (0*256+cb)*HH + kc*32 + qd*8);
                WZ[b2][kc] = ldfrag_f32(wih2 + (1*256+cb)*HH + kc*32 + qd*8);
                WN[b2][kc] = ldfrag_f32(wih2 + (2*256+cb)*HH + kc*32 + qd*8);
            }
            bR[b2] = bih2[cb]       + bhh2[cb];
            bZ[b2] = bih2[256 + cb] + bhh2[256 + cb];
            bN[b2] = bih2[512 + cb];
        }
        const u64* h1r = (const u64*)(ws + OFF_H1R);
        char* gi2 = ws + OFF_GI2;
        int cA = 0, cB = 0;
        const int pcol = tid >> 1, prow = (tid & 1) * 8;
        u64 c0, c1, n0, n1;
        ensure(pA, 1, cA);
        c0 = ld_u64_coh(h1r + (size_t)cl*RD*1024 + 2*tid);
        c1 = ld_u64_coh(h1r + (size_t)cl*RD*1024 + 2*tid + 1);
        __syncthreads();

        auto stepM2 = [&](int t, u64& v0, u64& v1, u64& w0, u64& w1) {
            WAITV(10); BARRIER();
            if (tid == 0 && t >= 1) post(pM2, t - 1);
            if (t + 1 < TT) {
                ensure(pA, t + 2, cA);
                const u64* hp = h1r + ((size_t)cl*RD + ((t+1) & 7))*1024;
                w0 = ld_u64_coh(hp + 2*tid);
                w1 = ld_u64_coh(hp + 2*tid + 1);
            }
            if ((t & 3) == 0) ensure(pB, t - 5, cB);
            // h1(t) relay -> LDS
            #pragma unroll
            for (int k = 0; k < 4; ++k) {
                hb[0][prow + k    ][pcol] = (short)(v0 >> (16*k));
                hb[0][prow + k + 4][pcol] = (short)(v1 >> (16*k));
            }
            BARRIER();
            f32x4 aR[2], aZ[2], aN[2];
            #pragma unroll
            for (int b2 = 0; b2 < 2; ++b2) {
                aR[b2] = f32x4{bR[b2],bR[b2],bR[b2],bR[b2]};
                aZ[b2] = f32x4{bZ[b2],bZ[b2],bZ[b2],bZ[b2]};
                aN[b2] = f32x4{bN[b2],bN[b2],bN[b2],bN[b2]};
            }
            #pragma unroll
            for (int kc = 0; kc < 8; ++kc) {
                bf16x8 f = *(const bf16x8*)&hb[0][ln][kc*32 + qd*8];
                aR[0] = MFMA16(f, WR[0][kc], aR[0]);
                aR[1] = MFMA16(f, WR[1][kc], aR[1]);
                aZ[0] = MFMA16(f, WZ[0][kc], aZ[0]);
                aZ[1] = MFMA16(f, WZ[1][kc], aZ[1]);
                aN[0] = MFMA16(f, WN[0][kc], aN[0]);
                aN[1] = MFMA16(f, WN[1][kc], aN[1]);
            }
            u64* gb = (u64*)(gi2 + ((size_t)cl*RD + (t & 7))*GI_SLOT);
            #pragma unroll
            for (int b2 = 0; b2 < 2; ++b2) {
                st_u64_coh(gb + tid*4 + b2*2,     pack4bf(aR[b2][0],aR[b2][1],aR[b2][2],aR[b2][3]));
                st_u64_coh(gb + tid*4 + b2*2 + 1, pack4bf(aZ[b2][0],aZ[b2][1],aZ[b2][2],aZ[b2][3]));
                union { f32x4 v; u64 u[2]; } nn; nn.v = aN[b2];
                st_u64_coh(gb + 2048 + tid*4 + b2*2,     nn.u[0]);
                st_u64_coh(gb + 2048 + tid*4 + b2*2 + 1, nn.u[1]);
            }
        };
        for (int t = 0; t < TT; t += 2) { stepM2(t, c0, c1, n0, n1); stepM2(t+1, n0, n1, c0, c1); }
        asm volatile("s_waitcnt vmcnt(0)" ::: "memory");
        __syncthreads();
        if (tid == 0) post(pM2, TT + 64);
    }
}

// ---------------- BN finalize + hardtanh + temporal mean + FC ----------------
// h2p layout: u64 at (cl*TT + t)*1024 + col*4 + grp, packing rows grp*4..grp*4+3
__global__ void __launch_bounds__(1024)
gru_final(const char* __restrict__ ws,
          const float* __restrict__ gamma, const float* __restrict__ beta,
          const float* __restrict__ fcw, const float* __restrict__ fcb,
          float* __restrict__ out)
{
    __shared__ float summ[16][HH];
    const int cl  = blockIdx.x;
    const int tid = threadIdx.x;
    const int col = tid & 255;
    const int grp = tid >> 8;
    const float* bnsum = (const float*)(ws + OFF_BNSUM);
    const float* bnsq  = (const float*)(ws + OFF_BNSQ);
    const u64* h2p = (const u64*)(ws + OFF_H2P);

    const float inv = 1.f / (float)(BB * TT);
    float mean  = bnsum[col] * inv;
    float var   = bnsq[col] * inv - mean * mean;
    float scale = rsqrtf(var + EPSV) * gamma[col];
    float shift = beta[col] - mean * scale;

    const u64* hp = h2p + (size_t)cl*TT*1024 + col*4 + grp;
    float acc[4] = {0,0,0,0};
    for (int t = 0; t < TT; ++t) {
        u64 v = hp[(size_t)t*1024];
        #pragma unroll
        for (int j = 0; j < 4; ++j) {
            float x = bf2f((short)(v >> (16*j))) * scale + shift;
            x = fminf(fmaxf(x, -2.f), 2.f);
            acc[j] += x;
        }
    }
    #pragma unroll
    for (int j = 0; j < 4; ++j) summ[grp*4 + j][col] = acc[j] * (1.f / TT);
    __syncthreads();

    #pragma unroll
    for (int rep = 0; rep < 2; ++rep) {
        int p = tid + rep * 1024;
        int b = p >> 7, o = p & 127;
        float d = fcb[o];
        const float* wr = fcw + o * HH;
        #pragma unroll 8
        for (int c = 0; c < HH; ++c) d += wr[c] * summ[b][c];
        out[(cl*16 + b) * OUTD + o] = d;
    }
}

extern "C" void kernel_launch(void* const* d_in, const int* in_sizes, int n_in,
                              void* d_out, int out_size, void* d_ws, size_t ws_size,
                              hipStream_t stream)
{
    const float* x    = (const float*)d_in[0];
    const float* wih1 = (const float*)d_in[1];
    const float* whh1 = (const float*)d_in[2];
    const float* bih1 = (const float*)d_in[3];
    const float* bhh1 = (const float*)d_in[4];
    const float* wih2 = (const float*)d_in[5];
    const float* whh2 = (const float*)d_in[6];
    const float* bih2 = (const float*)d_in[7];
    const float* bhh2 = (const float*)d_in[8];
    const float* gamma= (const float*)d_in[9];
    const float* beta = (const float*)d_in[10];
    const float* fcw  = (const float*)d_in[11];
    const float* fcb  = (const float*)d_in[12];
    char* ws = (char*)d_ws;

    (void)hipMemsetAsync(ws, 0, OFF_ZERO_END, stream);

    const int nx = BB*TT*II;
    hipLaunchKernelGGL(cvt_x, dim3(nx/4/256), dim3(256), 0, stream,
                       x, (short*)(ws + OFF_XBF), nx);

    hipLaunchKernelGGL(gru_pipe, dim3(NCL*4), dim3(512), 0, stream,
                       (const short*)(ws + OFF_XBF),
                       wih1, whh1, bih1, bhh1, wih2, whh2, bih2, bhh2, ws);

    hipLaunchKernelGGL(gru_final, dim3(NCL), dim3(1024), 0, stream,
                       (const char*)ws, gamma, beta, fcw, fcb, (float*)d_out);
}